// Round 1
// baseline (703.418 us; speedup 1.0000x reference)
//
#include <hip/hip_runtime.h>

typedef unsigned short u16;
typedef __bf16 bf16x8 __attribute__((ext_vector_type(8)));
typedef float f32x4 __attribute__((ext_vector_type(4)));

#define T_TOK 2048
#define HID   1024
#define NEXP  32
#define IM    512
#define SI    2048
#define TOPK  6

// exact RNE float->bf16
__device__ __forceinline__ u16 f2bf(float f){
  unsigned u = __float_as_uint(f);
  u += 0x7FFFu + ((u >> 16) & 1u);
  return (u16)(u >> 16);
}

__global__ __launch_bounds__(256) void cvt_kernel(const float4* __restrict__ in,
                                                  ushort4* __restrict__ out, int n4){
  int i = blockIdx.x * 256 + threadIdx.x;
  if (i >= n4) return;
  float4 v = in[i];
  ushort4 o; o.x = f2bf(v.x); o.y = f2bf(v.y); o.z = f2bf(v.z); o.w = f2bf(v.w);
  out[i] = o;
}

// one wave per token: fp64 logits + fp64 routing decisions (tie-flip safety)
__global__ __launch_bounds__(64) void router_kernel(const float* __restrict__ x,
                                                    const float* __restrict__ gate,
                                                    const float* __restrict__ ebias,
                                                    int* __restrict__ cnt,
                                                    int* __restrict__ tok,
                                                    float* __restrict__ wl){
  int t = blockIdx.x;
  int lane = threadIdx.x;
  int e = lane & 31, half = lane >> 5;
  const float4* xv = (const float4*)(x + (size_t)t * HID);
  const float4* gv = (const float4*)(gate + (size_t)e * HID);
  double acc = 0.0;
  for (int i = half * 128; i < half * 128 + 128; i++){
    float4 a = xv[i], b = gv[i];
    acc += (double)a.x * b.x + (double)a.y * b.y + (double)a.z * b.z + (double)a.w * b.w;
  }
  acc += __shfl_xor(acc, 32);
  __shared__ double s_score[32], s_sc[32], s_m[32], s_gs[8];
  if (lane < 32){
    double sg = 1.0 / (1.0 + exp(-acc));
    s_score[e] = sg;
    s_sc[e] = sg + (double)ebias[e];
  }
  __syncthreads();
  if (lane == 0){
    // group scores: top-2 sum within each group of 4
    for (int g = 0; g < 8; g++){
      double a = s_sc[4*g+0], b = s_sc[4*g+1], c = s_sc[4*g+2], d = s_sc[4*g+3];
      double hi1 = fmax(a,b), lo1 = fmin(a,b), hi2 = fmax(c,d), lo2 = fmin(c,d);
      s_gs[g] = (hi1 >= hi2) ? (hi1 + fmax(lo1, hi2)) : (hi2 + fmax(lo2, hi1));
    }
    // top-4 groups, strict > keeps lowest index (lax.top_k tie rule)
    unsigned gmask = 0;
    for (int it = 0; it < 4; it++){
      int best = 0; double bv = -1e300;
      for (int g = 0; g < 8; g++)
        if (!((gmask >> g) & 1u) && s_gs[g] > bv){ bv = s_gs[g]; best = g; }
      gmask |= 1u << best;
    }
    for (int i = 0; i < 32; i++) s_m[i] = ((gmask >> (i >> 2)) & 1u) ? s_sc[i] : 0.0;
    int idxs[TOPK]; double wsv[TOPK]; double wsum = 0.0;
    for (int it = 0; it < TOPK; it++){
      int best = 0; double bv = -1e300;
      for (int i = 0; i < 32; i++) if (s_m[i] > bv){ bv = s_m[i]; best = i; }
      idxs[it] = best; wsv[it] = s_score[best]; s_m[best] = -1e300; wsum += wsv[it];
    }
    double scale = 2.5 / (wsum + 1e-20);
    for (int k = 0; k < TOPK; k++){
      int ee = idxs[k];
      float w = (float)(wsv[k] * scale);
      int pos = atomicAdd(&cnt[ee], 1);
      tok[ee * T_TOK + pos] = (t << 3) | k;
      wl[ee * T_TOK + pos] = w;
    }
  }
}

// ---- common MFMA tile pattern: 64x64 block tile, 256 thr (4 waves), BK=32 ----
// A,B row-major [*,K] bf16 (NT gemm). A-frag: [m=lane&15][k=quad*8+j]; D: row=quad*4+r, col=lane&15.

// shared expert up: C[2048][2048] = bf16(relu2(X[2048][1024] . W[2048][1024]^T))
__global__ __launch_bounds__(256) void sh_up_kernel(const u16* __restrict__ A,
                                                    const u16* __restrict__ B,
                                                    u16* __restrict__ C){
  __shared__ u16 lA[64*40], lB[64*40];
  int bm = blockIdx.x * 64, bn = blockIdx.y * 64;
  int tid = threadIdx.x, wave = tid >> 6, lane = tid & 63, quad = lane >> 4, l16 = lane & 15;
  int srow = tid >> 2, seg = tid & 3;
  const u16* gA = A + (size_t)(bm + srow) * HID + seg * 8;
  const u16* gB = B + (size_t)(bn + srow) * HID + seg * 8;
  f32x4 acc[4] = {{0,0,0,0},{0,0,0,0},{0,0,0,0},{0,0,0,0}};
  for (int k0 = 0; k0 < HID; k0 += 32){
    *(uint4*)&lA[srow*40 + seg*8] = *(const uint4*)gA; gA += 32;
    *(uint4*)&lB[srow*40 + seg*8] = *(const uint4*)gB; gB += 32;
    __syncthreads();
    bf16x8 a = *(const bf16x8*)&lA[(wave*16 + l16)*40 + quad*8];
#pragma unroll
    for (int nt = 0; nt < 4; nt++){
      bf16x8 b = *(const bf16x8*)&lB[(nt*16 + l16)*40 + quad*8];
      acc[nt] = __builtin_amdgcn_mfma_f32_16x16x32_bf16(a, b, acc[nt], 0, 0, 0);
    }
    __syncthreads();
  }
#pragma unroll
  for (int nt = 0; nt < 4; nt++)
#pragma unroll
    for (int r = 0; r < 4; r++){
      int m = bm + wave*16 + quad*4 + r;
      int n = bn + nt*16 + l16;
      float v = acc[nt][r]; v = fmaxf(v, 0.f); v = v * v;
      C[(size_t)m * SI + n] = f2bf(v);
    }
}

// shared expert down: out[2048][1024] = H[2048][2048] . W[1024][2048]^T  (fp32 store)
__global__ __launch_bounds__(256) void sh_down_kernel(const u16* __restrict__ A,
                                                      const u16* __restrict__ B,
                                                      float* __restrict__ C){
  __shared__ u16 lA[64*40], lB[64*40];
  int bm = blockIdx.x * 64, bn = blockIdx.y * 64;
  int tid = threadIdx.x, wave = tid >> 6, lane = tid & 63, quad = lane >> 4, l16 = lane & 15;
  int srow = tid >> 2, seg = tid & 3;
  const u16* gA = A + (size_t)(bm + srow) * SI + seg * 8;
  const u16* gB = B + (size_t)(bn + srow) * SI + seg * 8;
  f32x4 acc[4] = {{0,0,0,0},{0,0,0,0},{0,0,0,0},{0,0,0,0}};
  for (int k0 = 0; k0 < SI; k0 += 32){
    *(uint4*)&lA[srow*40 + seg*8] = *(const uint4*)gA; gA += 32;
    *(uint4*)&lB[srow*40 + seg*8] = *(const uint4*)gB; gB += 32;
    __syncthreads();
    bf16x8 a = *(const bf16x8*)&lA[(wave*16 + l16)*40 + quad*8];
#pragma unroll
    for (int nt = 0; nt < 4; nt++){
      bf16x8 b = *(const bf16x8*)&lB[(nt*16 + l16)*40 + quad*8];
      acc[nt] = __builtin_amdgcn_mfma_f32_16x16x32_bf16(a, b, acc[nt], 0, 0, 0);
    }
    __syncthreads();
  }
#pragma unroll
  for (int nt = 0; nt < 4; nt++)
#pragma unroll
    for (int r = 0; r < 4; r++){
      int m = bm + wave*16 + quad*4 + r;
      int n = bn + nt*16 + l16;
      C[(size_t)m * HID + n] = acc[nt][r];
    }
}

// expert up: gathered rows; h_ws[t*6+k][512] = bf16(relu2(x_t . up_e^T) * w)
__global__ __launch_bounds__(256) void expert_up_kernel(const u16* __restrict__ xb,
                                                        const u16* __restrict__ upb,
                                                        const int* __restrict__ cnt,
                                                        const int* __restrict__ tok,
                                                        const float* __restrict__ wl,
                                                        u16* __restrict__ hws){
  int e = blockIdx.z;
  int c = cnt[e];
  int tb = blockIdx.x * 64;
  if (tb >= c) return;
  int bn = blockIdx.y * 64;
  const int* tl = tok + e * T_TOK;
  const float* wle = wl + e * T_TOK;
  __shared__ u16 lA[64*40], lB[64*40];
  int tid = threadIdx.x, wave = tid >> 6, lane = tid & 63, quad = lane >> 4, l16 = lane & 15;
  int srow = tid >> 2, seg = tid & 3;
  int sA = tb + srow; if (sA > c - 1) sA = c - 1;
  int tA = tl[sA] >> 3;
  const u16* gA = xb + (size_t)tA * HID + seg * 8;
  const u16* gB = upb + (size_t)e * IM * HID + (size_t)(bn + srow) * HID + seg * 8;
  f32x4 acc[4] = {{0,0,0,0},{0,0,0,0},{0,0,0,0},{0,0,0,0}};
  for (int k0 = 0; k0 < HID; k0 += 32){
    *(uint4*)&lA[srow*40 + seg*8] = *(const uint4*)gA; gA += 32;
    *(uint4*)&lB[srow*40 + seg*8] = *(const uint4*)gB; gB += 32;
    __syncthreads();
    bf16x8 a = *(const bf16x8*)&lA[(wave*16 + l16)*40 + quad*8];
#pragma unroll
    for (int nt = 0; nt < 4; nt++){
      bf16x8 b = *(const bf16x8*)&lB[(nt*16 + l16)*40 + quad*8];
      acc[nt] = __builtin_amdgcn_mfma_f32_16x16x32_bf16(a, b, acc[nt], 0, 0, 0);
    }
    __syncthreads();
  }
#pragma unroll
  for (int r = 0; r < 4; r++){
    int s = tb + wave*16 + quad*4 + r;
    if (s < c){
      int code = tl[s];
      int t = code >> 3, kk = code & 7;
      float w = wle[s];
      size_t hbase = ((size_t)t * TOPK + kk) * IM;
#pragma unroll
      for (int nt = 0; nt < 4; nt++){
        float v = acc[nt][r]; v = fmaxf(v, 0.f); v = v * v * w;
        hws[hbase + bn + nt*16 + l16] = f2bf(v);
      }
    }
  }
}

// expert down: out[t] += h_ws[t*6+k] . down_e^T  (atomicAdd fp32)
__global__ __launch_bounds__(256) void expert_down_kernel(const u16* __restrict__ hws,
                                                          const u16* __restrict__ dnb,
                                                          const int* __restrict__ cnt,
                                                          const int* __restrict__ tok,
                                                          float* __restrict__ out){
  int e = blockIdx.z;
  int c = cnt[e];
  int tb = blockIdx.x * 64;
  if (tb >= c) return;
  int bn = blockIdx.y * 64;
  const int* tl = tok + e * T_TOK;
  __shared__ u16 lA[64*40], lB[64*40];
  int tid = threadIdx.x, wave = tid >> 6, lane = tid & 63, quad = lane >> 4, l16 = lane & 15;
  int srow = tid >> 2, seg = tid & 3;
  int sA = tb + srow; if (sA > c - 1) sA = c - 1;
  int codeA = tl[sA];
  size_t hslot = (size_t)(codeA >> 3) * TOPK + (codeA & 7);
  const u16* gA = hws + hslot * IM + seg * 8;
  const u16* gB = dnb + (size_t)e * HID * IM + (size_t)(bn + srow) * IM + seg * 8;
  f32x4 acc[4] = {{0,0,0,0},{0,0,0,0},{0,0,0,0},{0,0,0,0}};
  for (int k0 = 0; k0 < IM; k0 += 32){
    *(uint4*)&lA[srow*40 + seg*8] = *(const uint4*)gA; gA += 32;
    *(uint4*)&lB[srow*40 + seg*8] = *(const uint4*)gB; gB += 32;
    __syncthreads();
    bf16x8 a = *(const bf16x8*)&lA[(wave*16 + l16)*40 + quad*8];
#pragma unroll
    for (int nt = 0; nt < 4; nt++){
      bf16x8 b = *(const bf16x8*)&lB[(nt*16 + l16)*40 + quad*8];
      acc[nt] = __builtin_amdgcn_mfma_f32_16x16x32_bf16(a, b, acc[nt], 0, 0, 0);
    }
    __syncthreads();
  }
#pragma unroll
  for (int r = 0; r < 4; r++){
    int s = tb + wave*16 + quad*4 + r;
    if (s < c){
      int t = tl[s] >> 3;
#pragma unroll
      for (int nt = 0; nt < 4; nt++){
        atomicAdd(&out[(size_t)t * HID + bn + nt*16 + l16], acc[nt][r]);
      }
    }
  }
}

extern "C" void kernel_launch(void* const* d_in, const int* in_sizes, int n_in,
                              void* d_out, int out_size, void* d_ws, size_t ws_size,
                              hipStream_t stream) {
  const float* x    = (const float*)d_in[0];  // [2048][1024]
  const float* gate = (const float*)d_in[1];  // [32][1024]
  const float* eb   = (const float*)d_in[2];  // [32]
  const float* upw  = (const float*)d_in[3];  // [32][512][1024]
  const float* dnw  = (const float*)d_in[4];  // [32][1024][512]
  const float* supw = (const float*)d_in[5];  // [2048][1024]
  const float* sdnw = (const float*)d_in[6];  // [1024][2048]
  float* out = (float*)d_out;                 // [2048][1024]

  char* w = (char*)d_ws;
  size_t o = 0;
  int*   cnt  = (int*)(w + o);   o += 1024;
  int*   tok  = (int*)(w + o);   o += (size_t)NEXP * T_TOK * 4;
  float* wl   = (float*)(w + o); o += (size_t)NEXP * T_TOK * 4;
  u16*   xb   = (u16*)(w + o);   o += (size_t)T_TOK * HID * 2;
  u16*   upb  = (u16*)(w + o);   o += (size_t)NEXP * IM * HID * 2;
  u16*   dnb  = (u16*)(w + o);   o += (size_t)NEXP * HID * IM * 2;
  u16*   supb = (u16*)(w + o);   o += (size_t)SI * HID * 2;
  u16*   sdnb = (u16*)(w + o);   o += (size_t)HID * SI * 2;
  u16*   shh  = (u16*)(w + o);   o += (size_t)T_TOK * SI * 2;
  u16*   hws  = (u16*)(w + o);   o += (size_t)T_TOK * TOPK * IM * 2;

  hipMemsetAsync(cnt, 0, 1024, stream);

  auto cv = [&](const float* src, u16* dst, int n){
    int n4 = n / 4;
    cvt_kernel<<<(n4 + 255) / 256, 256, 0, stream>>>((const float4*)src, (ushort4*)dst, n4);
  };
  cv(x,    xb,   T_TOK * HID);
  cv(upw,  upb,  NEXP * IM * HID);
  cv(dnw,  dnb,  NEXP * HID * IM);
  cv(supw, supb, SI * HID);
  cv(sdnw, sdnb, HID * SI);

  router_kernel<<<T_TOK, 64, 0, stream>>>(x, gate, eb, cnt, tok, wl);

  sh_up_kernel<<<dim3(T_TOK/64, SI/64), 256, 0, stream>>>(xb, supb, shh);
  sh_down_kernel<<<dim3(T_TOK/64, HID/64), 256, 0, stream>>>(shh, sdnb, out);

  expert_up_kernel<<<dim3(T_TOK/64, IM/64, NEXP), 256, 0, stream>>>(xb, upb, cnt, tok, wl, hws);
  expert_down_kernel<<<dim3(T_TOK/64, HID/64, NEXP), 256, 0, stream>>>(hws, dnb, cnt, tok, out);
}

// Round 2
// 588.537 us; speedup vs baseline: 1.1952x; 1.1952x over previous
//
#include <hip/hip_runtime.h>

typedef unsigned short u16;
typedef __bf16 bf16x8 __attribute__((ext_vector_type(8)));
typedef float f32x4 __attribute__((ext_vector_type(4)));

#define T_TOK 2048
#define HID   1024
#define NEXP  32
#define IM    512
#define SI    2048
#define TOPK  6

// exact RNE float->bf16
__device__ __forceinline__ u16 f2bf(float f){
  unsigned u = __float_as_uint(f);
  u += 0x7FFFu + ((u >> 16) & 1u);
  return (u16)(u >> 16);
}

// async global->LDS, 16B per lane. LDS dest must be wave-uniform base + lane*16.
__device__ __forceinline__ void gll16(const void* g, void* l){
  __builtin_amdgcn_global_load_lds((const __attribute__((address_space(1))) void*)g,
                                   (__attribute__((address_space(3))) void*)l, 16, 0, 0);
}

__global__ __launch_bounds__(256) void cvt_kernel(const float4* __restrict__ in,
                                                  ushort4* __restrict__ out, int n4){
  int i = blockIdx.x * 256 + threadIdx.x;
  if (i >= n4) return;
  float4 v = in[i];
  ushort4 o; o.x = f2bf(v.x); o.y = f2bf(v.y); o.z = f2bf(v.z); o.w = f2bf(v.w);
  out[i] = o;
}

// one wave per token: fp64 logits + fp64 routing decisions (tie-flip safety)
__global__ __launch_bounds__(64) void router_kernel(const float* __restrict__ x,
                                                    const float* __restrict__ gate,
                                                    const float* __restrict__ ebias,
                                                    int* __restrict__ cnt,
                                                    int* __restrict__ tok,
                                                    float* __restrict__ wl){
  int t = blockIdx.x;
  int lane = threadIdx.x;
  int e = lane & 31, half = lane >> 5;
  const float4* xv = (const float4*)(x + (size_t)t * HID);
  const float4* gv = (const float4*)(gate + (size_t)e * HID);
  double acc = 0.0;
  for (int i = half * 128; i < half * 128 + 128; i++){
    float4 a = xv[i], b = gv[i];
    acc += (double)a.x * b.x + (double)a.y * b.y + (double)a.z * b.z + (double)a.w * b.w;
  }
  acc += __shfl_xor(acc, 32);
  __shared__ double s_score[32], s_sc[32], s_m[32], s_gs[8];
  if (lane < 32){
    double sg = 1.0 / (1.0 + exp(-acc));
    s_score[e] = sg;
    s_sc[e] = sg + (double)ebias[e];
  }
  __syncthreads();
  if (lane == 0){
    for (int g = 0; g < 8; g++){
      double a = s_sc[4*g+0], b = s_sc[4*g+1], c = s_sc[4*g+2], d = s_sc[4*g+3];
      double hi1 = fmax(a,b), lo1 = fmin(a,b), hi2 = fmax(c,d), lo2 = fmin(c,d);
      s_gs[g] = (hi1 >= hi2) ? (hi1 + fmax(lo1, hi2)) : (hi2 + fmax(lo2, hi1));
    }
    unsigned gmask = 0;
    for (int it = 0; it < 4; it++){
      int best = 0; double bv = -1e300;
      for (int g = 0; g < 8; g++)
        if (!((gmask >> g) & 1u) && s_gs[g] > bv){ bv = s_gs[g]; best = g; }
      gmask |= 1u << best;
    }
    for (int i = 0; i < 32; i++) s_m[i] = ((gmask >> (i >> 2)) & 1u) ? s_sc[i] : 0.0;
    int idxs[TOPK]; double wsv[TOPK]; double wsum = 0.0;
    for (int it = 0; it < TOPK; it++){
      int best = 0; double bv = -1e300;
      for (int i = 0; i < 32; i++) if (s_m[i] > bv){ bv = s_m[i]; best = i; }
      idxs[it] = best; wsv[it] = s_score[best]; s_m[best] = -1e300; wsum += wsv[it];
    }
    double scale = 2.5 / (wsum + 1e-20);
    for (int k = 0; k < TOPK; k++){
      int ee = idxs[k];
      float w = (float)(wsv[k] * scale);
      int pos = atomicAdd(&cnt[ee], 1);
      tok[ee * T_TOK + pos] = (t << 3) | k;
      wl[ee * T_TOK + pos] = w;
    }
  }
}

// ---- m97-style core: 128x128 block tile, BK=32, 4 waves in 2x2, 4x4 MFMA acc/wave ----
// LDS tiles [128][32] u16 (8KB each), staged via global_load_lds in 2 passes of tid*16.
// A/B frag: [m|n = lane&15][k = quad*8+j]; C/D: row = quad*4 + r, col = lane&15.
__device__ __forceinline__ void gemm_core(
    const char* gA0, const char* gA1, const char* gB0, const char* gB1,
    u16* lA, u16* lB, int iters, int tid, int wrow, int wcol, int quad, int l16,
    f32x4 acc[4][4])
{
  char* dA0 = (char*)lA + tid*16;
  char* dA1 = (char*)lA + 4096 + tid*16;
  char* dB0 = (char*)lB + tid*16;
  char* dB1 = (char*)lB + 4096 + tid*16;
  for (int it = 0; it < iters; ++it){
    gll16(gA0, dA0); gll16(gA1, dA1);
    gll16(gB0, dB0); gll16(gB1, dB1);
    gA0 += 64; gA1 += 64; gB0 += 64; gB1 += 64;
    __syncthreads();
    bf16x8 af[4], bfr[4];
#pragma unroll
    for (int mt = 0; mt < 4; mt++) af[mt] = *(const bf16x8*)&lA[(wrow + mt*16 + l16)*32 + quad*8];
#pragma unroll
    for (int nt = 0; nt < 4; nt++) bfr[nt] = *(const bf16x8*)&lB[(wcol + nt*16 + l16)*32 + quad*8];
#pragma unroll
    for (int mt = 0; mt < 4; mt++)
#pragma unroll
      for (int nt = 0; nt < 4; nt++)
        acc[mt][nt] = __builtin_amdgcn_mfma_f32_16x16x32_bf16(af[mt], bfr[nt], acc[mt][nt], 0, 0, 0);
    __syncthreads();
  }
}

#define ACC_INIT f32x4 acc[4][4]; \
  _Pragma("unroll") for (int i_ = 0; i_ < 4; i_++) \
  _Pragma("unroll") for (int j_ = 0; j_ < 4; j_++) acc[i_][j_] = (f32x4){0.f,0.f,0.f,0.f};

// shared up: C[2048][2048] = bf16(relu2(X[2048][1024] . W[2048][1024]^T))
__global__ __launch_bounds__(256) void sh_up_kernel(const u16* __restrict__ A,
                                                    const u16* __restrict__ B,
                                                    u16* __restrict__ C){
  __shared__ u16 lA[128*32], lB[128*32];
  int tid = threadIdx.x;
  int bm = blockIdx.x*128, bn = blockIdx.y*128;
  int lane = tid & 63, wave = tid >> 6, quad = lane >> 4, l16 = lane & 15;
  int wrow = (wave >> 1)*64, wcol = (wave & 1)*64;
  int srow = tid >> 2, sseg = (tid & 3)*16;
  const char* gA0 = (const char*)(A + (size_t)(bm + srow)*HID) + sseg;
  const char* gA1 = (const char*)(A + (size_t)(bm + 64 + srow)*HID) + sseg;
  const char* gB0 = (const char*)(B + (size_t)(bn + srow)*HID) + sseg;
  const char* gB1 = (const char*)(B + (size_t)(bn + 64 + srow)*HID) + sseg;
  ACC_INIT;
  gemm_core(gA0, gA1, gB0, gB1, lA, lB, HID/32, tid, wrow, wcol, quad, l16, acc);
#pragma unroll
  for (int mt = 0; mt < 4; mt++)
#pragma unroll
    for (int nt = 0; nt < 4; nt++)
#pragma unroll
      for (int r = 0; r < 4; r++){
        int m = bm + wrow + mt*16 + quad*4 + r;
        int n = bn + wcol + nt*16 + l16;
        float v = acc[mt][nt][r]; v = fmaxf(v, 0.f); v *= v;
        C[(size_t)m*SI + n] = f2bf(v);
      }
}

// shared down: out[2048][1024] = H[2048][2048] . W[1024][2048]^T (fp32)
__global__ __launch_bounds__(256) void sh_down_kernel(const u16* __restrict__ A,
                                                      const u16* __restrict__ B,
                                                      float* __restrict__ C){
  __shared__ u16 lA[128*32], lB[128*32];
  int tid = threadIdx.x;
  int bm = blockIdx.x*128, bn = blockIdx.y*128;
  int lane = tid & 63, wave = tid >> 6, quad = lane >> 4, l16 = lane & 15;
  int wrow = (wave >> 1)*64, wcol = (wave & 1)*64;
  int srow = tid >> 2, sseg = (tid & 3)*16;
  const char* gA0 = (const char*)(A + (size_t)(bm + srow)*SI) + sseg;
  const char* gA1 = (const char*)(A + (size_t)(bm + 64 + srow)*SI) + sseg;
  const char* gB0 = (const char*)(B + (size_t)(bn + srow)*SI) + sseg;
  const char* gB1 = (const char*)(B + (size_t)(bn + 64 + srow)*SI) + sseg;
  ACC_INIT;
  gemm_core(gA0, gA1, gB0, gB1, lA, lB, SI/32, tid, wrow, wcol, quad, l16, acc);
#pragma unroll
  for (int mt = 0; mt < 4; mt++)
#pragma unroll
    for (int nt = 0; nt < 4; nt++)
#pragma unroll
      for (int r = 0; r < 4; r++){
        int m = bm + wrow + mt*16 + quad*4 + r;
        int n = bn + wcol + nt*16 + l16;
        C[(size_t)m*HID + n] = acc[mt][nt][r];
      }
}

// expert up: hws[t*6+k][512] = bf16(relu2(x_t . up_e^T) * w)
__global__ __launch_bounds__(256) void expert_up_kernel(const u16* __restrict__ xb,
                                                        const u16* __restrict__ upb,
                                                        const int* __restrict__ cnt,
                                                        const int* __restrict__ tok,
                                                        const float* __restrict__ wl,
                                                        u16* __restrict__ hws){
  int e = blockIdx.z;
  int c = cnt[e];
  int tb = blockIdx.x * 128;
  if (tb >= c) return;
  int bn = blockIdx.y * 128;
  const int* tl = tok + e * T_TOK;
  const float* wle = wl + e * T_TOK;
  __shared__ u16 lA[128*32], lB[128*32];
  int tid = threadIdx.x;
  int lane = tid & 63, wave = tid >> 6, quad = lane >> 4, l16 = lane & 15;
  int wrow = (wave >> 1)*64, wcol = (wave & 1)*64;
  int srow = tid >> 2, sseg = (tid & 3)*16;
  int s0 = tb + srow;      if (s0 > c-1) s0 = c-1;
  int s1 = tb + 64 + srow; if (s1 > c-1) s1 = c-1;
  int t0 = tl[s0] >> 3, t1 = tl[s1] >> 3;
  const char* gA0 = (const char*)(xb + (size_t)t0*HID) + sseg;
  const char* gA1 = (const char*)(xb + (size_t)t1*HID) + sseg;
  const u16* Bb = upb + (size_t)e * IM * HID;
  const char* gB0 = (const char*)(Bb + (size_t)(bn + srow)*HID) + sseg;
  const char* gB1 = (const char*)(Bb + (size_t)(bn + 64 + srow)*HID) + sseg;
  ACC_INIT;
  gemm_core(gA0, gA1, gB0, gB1, lA, lB, HID/32, tid, wrow, wcol, quad, l16, acc);
#pragma unroll
  for (int mt = 0; mt < 4; mt++)
#pragma unroll
    for (int r = 0; r < 4; r++){
      int s = tb + wrow + mt*16 + quad*4 + r;
      if (s < c){
        int code = tl[s];
        float w = wle[s];
        size_t hb = ((size_t)(code >> 3) * TOPK + (code & 7)) * IM;
#pragma unroll
        for (int nt = 0; nt < 4; nt++){
          float v = acc[mt][nt][r]; v = fmaxf(v, 0.f); v = v * v * w;
          hws[hb + bn + wcol + nt*16 + l16] = f2bf(v);
        }
      }
    }
}

// expert down: dws[t*6+k][1024] = h_slot . down_e^T (fp32, no atomics)
__global__ __launch_bounds__(256) void expert_down_kernel(const u16* __restrict__ hws,
                                                          const u16* __restrict__ dnb,
                                                          const int* __restrict__ cnt,
                                                          const int* __restrict__ tok,
                                                          float* __restrict__ dws){
  int e = blockIdx.z;
  int c = cnt[e];
  int tb = blockIdx.x * 128;
  if (tb >= c) return;
  int bn = blockIdx.y * 128;
  const int* tl = tok + e * T_TOK;
  __shared__ u16 lA[128*32], lB[128*32];
  int tid = threadIdx.x;
  int lane = tid & 63, wave = tid >> 6, quad = lane >> 4, l16 = lane & 15;
  int wrow = (wave >> 1)*64, wcol = (wave & 1)*64;
  int srow = tid >> 2, sseg = (tid & 3)*16;
  int s0 = tb + srow;      if (s0 > c-1) s0 = c-1;
  int s1 = tb + 64 + srow; if (s1 > c-1) s1 = c-1;
  int c0 = tl[s0], c1 = tl[s1];
  const char* gA0 = (const char*)(hws + ((size_t)(c0 >> 3)*TOPK + (c0 & 7))*IM) + sseg;
  const char* gA1 = (const char*)(hws + ((size_t)(c1 >> 3)*TOPK + (c1 & 7))*IM) + sseg;
  const u16* Bb = dnb + (size_t)e * HID * IM;
  const char* gB0 = (const char*)(Bb + (size_t)(bn + srow)*IM) + sseg;
  const char* gB1 = (const char*)(Bb + (size_t)(bn + 64 + srow)*IM) + sseg;
  ACC_INIT;
  gemm_core(gA0, gA1, gB0, gB1, lA, lB, IM/32, tid, wrow, wcol, quad, l16, acc);
#pragma unroll
  for (int mt = 0; mt < 4; mt++)
#pragma unroll
    for (int r = 0; r < 4; r++){
      int s = tb + wrow + mt*16 + quad*4 + r;
      if (s < c){
        int code = tl[s];
        size_t db = ((size_t)(code >> 3) * TOPK + (code & 7)) * HID;
#pragma unroll
        for (int nt = 0; nt < 4; nt++)
          dws[db + bn + wcol + nt*16 + l16] = acc[mt][nt][r];
      }
    }
}

// out[t][h] += sum_k dws[t*6+k][h]
__global__ __launch_bounds__(256) void reduce_kernel(const float4* __restrict__ dws,
                                                     float4* __restrict__ out){
  int i = blockIdx.x * 256 + threadIdx.x;   // over T*HID/4
  int t = i >> 8;                            // HID/4 = 256
  int col = i & 255;
  const float4* p = dws + (size_t)t * TOPK * 256 + col;
  float4 s = out[i];
#pragma unroll
  for (int k = 0; k < TOPK; k++){
    float4 v = p[(size_t)k * 256];
    s.x += v.x; s.y += v.y; s.z += v.z; s.w += v.w;
  }
  out[i] = s;
}

extern "C" void kernel_launch(void* const* d_in, const int* in_sizes, int n_in,
                              void* d_out, int out_size, void* d_ws, size_t ws_size,
                              hipStream_t stream) {
  const float* x    = (const float*)d_in[0];
  const float* gate = (const float*)d_in[1];
  const float* eb   = (const float*)d_in[2];
  const float* upw  = (const float*)d_in[3];
  const float* dnw  = (const float*)d_in[4];
  const float* supw = (const float*)d_in[5];
  const float* sdnw = (const float*)d_in[6];
  float* out = (float*)d_out;

  char* w = (char*)d_ws;
  size_t o = 0;
  int*   cnt  = (int*)(w + o);   o += 1024;
  int*   tok  = (int*)(w + o);   o += (size_t)NEXP * T_TOK * 4;
  float* wl   = (float*)(w + o); o += (size_t)NEXP * T_TOK * 4;
  u16*   xb   = (u16*)(w + o);   o += (size_t)T_TOK * HID * 2;
  u16*   dnb  = (u16*)(w + o);   o += (size_t)NEXP * HID * IM * 2;
  u16*   hws  = (u16*)(w + o);   o += (size_t)T_TOK * TOPK * IM * 2;
  // region reused: [upb | supb | sdnb | shh] all dead once expert_down runs -> dws aliases it
  size_t region = o;
  u16*   upb  = (u16*)(w + o);   o += (size_t)NEXP * IM * HID * 2;   // 32MB
  u16*   supb = (u16*)(w + o);   o += (size_t)SI * HID * 2;          // 8MB
  u16*   sdnb = (u16*)(w + o);   o += (size_t)HID * SI * 2;          // 8MB
  u16*   shh  = (u16*)(w + o);   o += (size_t)T_TOK * SI * 2;        // 8MB
  float* dws  = (float*)(w + region);  // 48MB <= 56MB region

  hipMemsetAsync(cnt, 0, 1024, stream);

  auto cv = [&](const float* src, u16* dst, int n){
    int n4 = n / 4;
    cvt_kernel<<<(n4 + 255) / 256, 256, 0, stream>>>((const float4*)src, (ushort4*)dst, n4);
  };
  cv(x,    xb,   T_TOK * HID);
  cv(upw,  upb,  NEXP * IM * HID);
  cv(dnw,  dnb,  NEXP * HID * IM);
  cv(supw, supb, SI * HID);
  cv(sdnw, sdnb, HID * SI);

  router_kernel<<<T_TOK, 64, 0, stream>>>(x, gate, eb, cnt, tok, wl);

  sh_up_kernel<<<dim3(T_TOK/128, SI/128), 256, 0, stream>>>(xb, supb, shh);
  sh_down_kernel<<<dim3(T_TOK/128, HID/128), 256, 0, stream>>>(shh, sdnb, out);

  expert_up_kernel<<<dim3(T_TOK/128, IM/128, NEXP), 256, 0, stream>>>(xb, upb, cnt, tok, wl, hws);
  expert_down_kernel<<<dim3(T_TOK/128, HID/128, NEXP), 256, 0, stream>>>(hws, dnb, cnt, tok, dws);

  reduce_kernel<<<(T_TOK * HID / 4) / 256, 256, 0, stream>>>((const float4*)dws, (float4*)out);
}

// Round 3
// 581.517 us; speedup vs baseline: 1.2096x; 1.0121x over previous
//
#include <hip/hip_runtime.h>

typedef unsigned short u16;
typedef __bf16 bf16x8 __attribute__((ext_vector_type(8)));
typedef float f32x4 __attribute__((ext_vector_type(4)));

#define T_TOK 2048
#define HID   1024
#define NEXP  32
#define IM    512
#define SI    2048
#define TOPK  6

// exact RNE float->bf16
__device__ __forceinline__ u16 f2bf(float f){
  unsigned u = __float_as_uint(f);
  u += 0x7FFFu + ((u >> 16) & 1u);
  return (u16)(u >> 16);
}

// async global->LDS, 16B per lane. LDS dest must be wave-uniform base + lane*16.
__device__ __forceinline__ void gll16(const void* g, void* l){
  __builtin_amdgcn_global_load_lds((const __attribute__((address_space(1))) void*)g,
                                   (__attribute__((address_space(3))) void*)l, 16, 0, 0);
}

__global__ __launch_bounds__(256) void cvt_kernel(const float4* __restrict__ in,
                                                  ushort4* __restrict__ out, int n4){
  int i = blockIdx.x * 256 + threadIdx.x;
  if (i >= n4) return;
  float4 v = in[i];
  ushort4 o; o.x = f2bf(v.x); o.y = f2bf(v.y); o.z = f2bf(v.z); o.w = f2bf(v.w);
  out[i] = o;
}

// router v2: 4 tokens/block, 1 wave/token, all-register cross-lane top-k (no LDS).
// fp64 logits + fp64 decisions; tie rule = lowest index (lax.top_k).
__global__ __launch_bounds__(256) void router_kernel(const float* __restrict__ x,
                                                     const float* __restrict__ gate,
                                                     const float* __restrict__ ebias,
                                                     int* __restrict__ cnt,
                                                     int* __restrict__ tok,
                                                     float* __restrict__ wl){
  int wave = threadIdx.x >> 6;
  int lane = threadIdx.x & 63;
  int t = blockIdx.x * 4 + wave;
  int e = lane & 31, half = lane >> 5;
  const float4* xv = (const float4*)(x + (size_t)t * HID);
  const float4* gv = (const float4*)(gate + (size_t)e * HID);
  double d0 = 0, d1 = 0, d2 = 0, d3 = 0;
  for (int i = half * 128; i < half * 128 + 128; i++){
    float4 a = xv[i], b = gv[i];
    d0 += (double)a.x * b.x; d1 += (double)a.y * b.y;
    d2 += (double)a.z * b.z; d3 += (double)a.w * b.w;
  }
  double acc = (d0 + d1) + (d2 + d3);
  acc += __shfl_xor(acc, 32);                 // full dot in all 64 lanes (halves duplicate)
  double score = 1.0 / (1.0 + exp(-acc));     // unbiased sigmoid score for expert e
  double sc = score + (double)ebias[e];
  // group score: top-2 sum within each group of 4 consecutive experts
  double o1  = __shfl_xor(sc, 1);
  double hi  = fmax(sc, o1), lo = fmin(sc, o1);
  double ohi = __shfl_xor(hi, 2), olo = __shfl_xor(lo, 2);
  double gs  = (hi >= ohi) ? hi + fmax(lo, ohi) : ohi + fmax(olo, hi);
  // rank my group among the 8 group scores (tie -> lower group idx)
  int g = e >> 2;
  int rank = 0;
#pragma unroll
  for (int j = 0; j < 8; j++){
    double gj = __shfl(gs, j * 4);
    if (gj > gs || (gj == gs && j < g)) rank++;
  }
  double cur = (rank < 4) ? sc : 0.0;         // masked score (all sc>0 so 0 excludes)
  // top-6 via 6 rounds of 64-lane butterfly argmax (lowest lane wins ties,
  // so the lane<32 copy of each duplicated expert is reported)
  int sel_e[TOPK]; double sel_w[TOPK]; double wsum = 0.0;
#pragma unroll
  for (int k = 0; k < TOPK; k++){
    double bv = cur; int bi = lane;
#pragma unroll
    for (int m = 32; m >= 1; m >>= 1){
      double ov = __shfl_xor(bv, m); int oi = __shfl_xor(bi, m);
      if (ov > bv || (ov == bv && oi < bi)) { bv = ov; bi = oi; }
    }
    if ((bi & 31) == e) cur = -1e300;         // both duplicate copies mask the winner
    double ws = __shfl(score, bi);
    sel_e[k] = bi; sel_w[k] = ws; wsum += ws;
  }
  double scale = 2.5 / (wsum + 1e-20);
#pragma unroll
  for (int k = 0; k < TOPK; k++){
    if (lane == k){                            // compile-time index -> stays in registers
      int ee = sel_e[k];
      float wv = (float)(sel_w[k] * scale);
      int pos = atomicAdd(&cnt[ee], 1);
      tok[ee * T_TOK + pos] = (t << 3) | k;
      wl[ee * T_TOK + pos] = wv;
    }
  }
}

// ---- m97-style core: 128x128 block tile, BK=32, 4 waves in 2x2, 4x4 MFMA acc/wave ----
__device__ __forceinline__ void gemm_core(
    const char* gA0, const char* gA1, const char* gB0, const char* gB1,
    u16* lA, u16* lB, int iters, int tid, int wrow, int wcol, int quad, int l16,
    f32x4 acc[4][4])
{
  char* dA0 = (char*)lA + tid*16;
  char* dA1 = (char*)lA + 4096 + tid*16;
  char* dB0 = (char*)lB + tid*16;
  char* dB1 = (char*)lB + 4096 + tid*16;
  for (int it = 0; it < iters; ++it){
    gll16(gA0, dA0); gll16(gA1, dA1);
    gll16(gB0, dB0); gll16(gB1, dB1);
    gA0 += 64; gA1 += 64; gB0 += 64; gB1 += 64;
    __syncthreads();
    bf16x8 af[4], bfr[4];
#pragma unroll
    for (int mt = 0; mt < 4; mt++) af[mt] = *(const bf16x8*)&lA[(wrow + mt*16 + l16)*32 + quad*8];
#pragma unroll
    for (int nt = 0; nt < 4; nt++) bfr[nt] = *(const bf16x8*)&lB[(wcol + nt*16 + l16)*32 + quad*8];
#pragma unroll
    for (int mt = 0; mt < 4; mt++)
#pragma unroll
      for (int nt = 0; nt < 4; nt++)
        acc[mt][nt] = __builtin_amdgcn_mfma_f32_16x16x32_bf16(af[mt], bfr[nt], acc[mt][nt], 0, 0, 0);
    __syncthreads();
  }
}

#define ACC_INIT f32x4 acc[4][4]; \
  _Pragma("unroll") for (int i_ = 0; i_ < 4; i_++) \
  _Pragma("unroll") for (int j_ = 0; j_ < 4; j_++) acc[i_][j_] = (f32x4){0.f,0.f,0.f,0.f};

// shared up: C[2048][2048] = bf16(relu2(X[2048][1024] . W[2048][1024]^T))
__global__ __launch_bounds__(256) void sh_up_kernel(const u16* __restrict__ A,
                                                    const u16* __restrict__ B,
                                                    u16* __restrict__ C){
  __shared__ u16 lA[128*32], lB[128*32];
  int tid = threadIdx.x;
  int bm = blockIdx.x*128, bn = blockIdx.y*128;
  int lane = tid & 63, wave = tid >> 6, quad = lane >> 4, l16 = lane & 15;
  int wrow = (wave >> 1)*64, wcol = (wave & 1)*64;
  int srow = tid >> 2, sseg = (tid & 3)*16;
  const char* gA0 = (const char*)(A + (size_t)(bm + srow)*HID) + sseg;
  const char* gA1 = (const char*)(A + (size_t)(bm + 64 + srow)*HID) + sseg;
  const char* gB0 = (const char*)(B + (size_t)(bn + srow)*HID) + sseg;
  const char* gB1 = (const char*)(B + (size_t)(bn + 64 + srow)*HID) + sseg;
  ACC_INIT;
  gemm_core(gA0, gA1, gB0, gB1, lA, lB, HID/32, tid, wrow, wcol, quad, l16, acc);
#pragma unroll
  for (int mt = 0; mt < 4; mt++)
#pragma unroll
    for (int nt = 0; nt < 4; nt++)
#pragma unroll
      for (int r = 0; r < 4; r++){
        int m = bm + wrow + mt*16 + quad*4 + r;
        int n = bn + wcol + nt*16 + l16;
        float v = acc[mt][nt][r]; v = fmaxf(v, 0.f); v *= v;
        C[(size_t)m*SI + n] = f2bf(v);
      }
}

// shared down: out[2048][1024] = H[2048][2048] . W[1024][2048]^T (fp32)
__global__ __launch_bounds__(256) void sh_down_kernel(const u16* __restrict__ A,
                                                      const u16* __restrict__ B,
                                                      float* __restrict__ C){
  __shared__ u16 lA[128*32], lB[128*32];
  int tid = threadIdx.x;
  int bm = blockIdx.x*128, bn = blockIdx.y*128;
  int lane = tid & 63, wave = tid >> 6, quad = lane >> 4, l16 = lane & 15;
  int wrow = (wave >> 1)*64, wcol = (wave & 1)*64;
  int srow = tid >> 2, sseg = (tid & 3)*16;
  const char* gA0 = (const char*)(A + (size_t)(bm + srow)*SI) + sseg;
  const char* gA1 = (const char*)(A + (size_t)(bm + 64 + srow)*SI) + sseg;
  const char* gB0 = (const char*)(B + (size_t)(bn + srow)*SI) + sseg;
  const char* gB1 = (const char*)(B + (size_t)(bn + 64 + srow)*SI) + sseg;
  ACC_INIT;
  gemm_core(gA0, gA1, gB0, gB1, lA, lB, SI/32, tid, wrow, wcol, quad, l16, acc);
#pragma unroll
  for (int mt = 0; mt < 4; mt++)
#pragma unroll
    for (int nt = 0; nt < 4; nt++)
#pragma unroll
      for (int r = 0; r < 4; r++){
        int m = bm + wrow + mt*16 + quad*4 + r;
        int n = bn + wcol + nt*16 + l16;
        C[(size_t)m*HID + n] = acc[mt][nt][r];
      }
}

// expert up: hws[t*6+k][512] = bf16(relu2(x_t . up_e^T) * w)
__global__ __launch_bounds__(256) void expert_up_kernel(const u16* __restrict__ xb,
                                                        const u16* __restrict__ upb,
                                                        const int* __restrict__ cnt,
                                                        const int* __restrict__ tok,
                                                        const float* __restrict__ wl,
                                                        u16* __restrict__ hws){
  int e = blockIdx.z;
  int c = cnt[e];
  int tb = blockIdx.x * 128;
  if (tb >= c) return;
  int bn = blockIdx.y * 128;
  const int* tl = tok + e * T_TOK;
  const float* wle = wl + e * T_TOK;
  __shared__ u16 lA[128*32], lB[128*32];
  int tid = threadIdx.x;
  int lane = tid & 63, wave = tid >> 6, quad = lane >> 4, l16 = lane & 15;
  int wrow = (wave >> 1)*64, wcol = (wave & 1)*64;
  int srow = tid >> 2, sseg = (tid & 3)*16;
  int s0 = tb + srow;      if (s0 > c-1) s0 = c-1;
  int s1 = tb + 64 + srow; if (s1 > c-1) s1 = c-1;
  int t0 = tl[s0] >> 3, t1 = tl[s1] >> 3;
  const char* gA0 = (const char*)(xb + (size_t)t0*HID) + sseg;
  const char* gA1 = (const char*)(xb + (size_t)t1*HID) + sseg;
  const u16* Bb = upb + (size_t)e * IM * HID;
  const char* gB0 = (const char*)(Bb + (size_t)(bn + srow)*HID) + sseg;
  const char* gB1 = (const char*)(Bb + (size_t)(bn + 64 + srow)*HID) + sseg;
  ACC_INIT;
  gemm_core(gA0, gA1, gB0, gB1, lA, lB, HID/32, tid, wrow, wcol, quad, l16, acc);
#pragma unroll
  for (int mt = 0; mt < 4; mt++)
#pragma unroll
    for (int r = 0; r < 4; r++){
      int s = tb + wrow + mt*16 + quad*4 + r;
      if (s < c){
        int code = tl[s];
        float w = wle[s];
        size_t hb = ((size_t)(code >> 3) * TOPK + (code & 7)) * IM;
#pragma unroll
        for (int nt = 0; nt < 4; nt++){
          float v = acc[mt][nt][r]; v = fmaxf(v, 0.f); v = v * v * w;
          hws[hb + bn + wcol + nt*16 + l16] = f2bf(v);
        }
      }
    }
}

// expert down: dws[t*6+k][1024] = h_slot . down_e^T (fp32, no atomics)
__global__ __launch_bounds__(256) void expert_down_kernel(const u16* __restrict__ hws,
                                                          const u16* __restrict__ dnb,
                                                          const int* __restrict__ cnt,
                                                          const int* __restrict__ tok,
                                                          float* __restrict__ dws){
  int e = blockIdx.z;
  int c = cnt[e];
  int tb = blockIdx.x * 128;
  if (tb >= c) return;
  int bn = blockIdx.y * 128;
  const int* tl = tok + e * T_TOK;
  __shared__ u16 lA[128*32], lB[128*32];
  int tid = threadIdx.x;
  int lane = tid & 63, wave = tid >> 6, quad = lane >> 4, l16 = lane & 15;
  int wrow = (wave >> 1)*64, wcol = (wave & 1)*64;
  int srow = tid >> 2, sseg = (tid & 3)*16;
  int s0 = tb + srow;      if (s0 > c-1) s0 = c-1;
  int s1 = tb + 64 + srow; if (s1 > c-1) s1 = c-1;
  int c0 = tl[s0], c1 = tl[s1];
  const char* gA0 = (const char*)(hws + ((size_t)(c0 >> 3)*TOPK + (c0 & 7))*IM) + sseg;
  const char* gA1 = (const char*)(hws + ((size_t)(c1 >> 3)*TOPK + (c1 & 7))*IM) + sseg;
  const u16* Bb = dnb + (size_t)e * HID * IM;
  const char* gB0 = (const char*)(Bb + (size_t)(bn + srow)*IM) + sseg;
  const char* gB1 = (const char*)(Bb + (size_t)(bn + 64 + srow)*IM) + sseg;
  ACC_INIT;
  gemm_core(gA0, gA1, gB0, gB1, lA, lB, IM/32, tid, wrow, wcol, quad, l16, acc);
#pragma unroll
  for (int mt = 0; mt < 4; mt++)
#pragma unroll
    for (int r = 0; r < 4; r++){
      int s = tb + wrow + mt*16 + quad*4 + r;
      if (s < c){
        int code = tl[s];
        size_t db = ((size_t)(code >> 3) * TOPK + (code & 7)) * HID;
#pragma unroll
        for (int nt = 0; nt < 4; nt++)
          dws[db + bn + wcol + nt*16 + l16] = acc[mt][nt][r];
      }
    }
}

// out[t][h] += sum_k dws[t*6+k][h]
__global__ __launch_bounds__(256) void reduce_kernel(const float4* __restrict__ dws,
                                                     float4* __restrict__ out){
  int i = blockIdx.x * 256 + threadIdx.x;   // over T*HID/4
  int t = i >> 8;                            // HID/4 = 256
  int col = i & 255;
  const float4* p = dws + (size_t)t * TOPK * 256 + col;
  float4 s = out[i];
#pragma unroll
  for (int k = 0; k < TOPK; k++){
    float4 v = p[(size_t)k * 256];
    s.x += v.x; s.y += v.y; s.z += v.z; s.w += v.w;
  }
  out[i] = s;
}

extern "C" void kernel_launch(void* const* d_in, const int* in_sizes, int n_in,
                              void* d_out, int out_size, void* d_ws, size_t ws_size,
                              hipStream_t stream) {
  const float* x    = (const float*)d_in[0];
  const float* gate = (const float*)d_in[1];
  const float* eb   = (const float*)d_in[2];
  const float* upw  = (const float*)d_in[3];
  const float* dnw  = (const float*)d_in[4];
  const float* supw = (const float*)d_in[5];
  const float* sdnw = (const float*)d_in[6];
  float* out = (float*)d_out;

  char* w = (char*)d_ws;
  size_t o = 0;
  int*   cnt  = (int*)(w + o);   o += 1024;
  int*   tok  = (int*)(w + o);   o += (size_t)NEXP * T_TOK * 4;
  float* wl   = (float*)(w + o); o += (size_t)NEXP * T_TOK * 4;
  u16*   xb   = (u16*)(w + o);   o += (size_t)T_TOK * HID * 2;
  u16*   dnb  = (u16*)(w + o);   o += (size_t)NEXP * HID * IM * 2;
  u16*   hws  = (u16*)(w + o);   o += (size_t)T_TOK * TOPK * IM * 2;
  // region reused: [upb | supb | sdnb | shh] all dead once expert_down runs -> dws aliases it
  size_t region = o;
  u16*   upb  = (u16*)(w + o);   o += (size_t)NEXP * IM * HID * 2;   // 32MB
  u16*   supb = (u16*)(w + o);   o += (size_t)SI * HID * 2;          // 8MB
  u16*   sdnb = (u16*)(w + o);   o += (size_t)HID * SI * 2;          // 8MB
  u16*   shh  = (u16*)(w + o);   o += (size_t)T_TOK * SI * 2;        // 8MB
  float* dws  = (float*)(w + region);  // 48MB <= 56MB region

  hipMemsetAsync(cnt, 0, 1024, stream);

  auto cv = [&](const float* src, u16* dst, int n){
    int n4 = n / 4;
    cvt_kernel<<<(n4 + 255) / 256, 256, 0, stream>>>((const float4*)src, (ushort4*)dst, n4);
  };
  cv(x,    xb,   T_TOK * HID);
  cv(upw,  upb,  NEXP * IM * HID);
  cv(dnw,  dnb,  NEXP * HID * IM);
  cv(supw, supb, SI * HID);
  cv(sdnw, sdnb, HID * SI);

  router_kernel<<<T_TOK/4, 256, 0, stream>>>(x, gate, eb, cnt, tok, wl);

  sh_up_kernel<<<dim3(T_TOK/128, SI/128), 256, 0, stream>>>(xb, supb, shh);
  sh_down_kernel<<<dim3(T_TOK/128, HID/128), 256, 0, stream>>>(shh, sdnb, out);

  expert_up_kernel<<<dim3(T_TOK/128, IM/128, NEXP), 256, 0, stream>>>(xb, upb, cnt, tok, wl, hws);
  expert_down_kernel<<<dim3(T_TOK/128, HID/128, NEXP), 256, 0, stream>>>(hws, dnb, cnt, tok, dws);

  reduce_kernel<<<(T_TOK * HID / 4) / 256, 256, 0, stream>>>((const float4*)dws, (float4*)out);
}

// Round 4
// 445.475 us; speedup vs baseline: 1.5790x; 1.3054x over previous
//
#include <hip/hip_runtime.h>

typedef unsigned short u16;
typedef __bf16 bf16x8 __attribute__((ext_vector_type(8)));
typedef float f32x4 __attribute__((ext_vector_type(4)));

#define T_TOK 2048
#define HID   1024
#define NEXP  32
#define IM    512
#define SI    2048
#define TOPK  6
#define PLAN_MAX 160

// exact RNE float->bf16
__device__ __forceinline__ u16 f2bf(float f){
  unsigned u = __float_as_uint(f);
  u += 0x7FFFu + ((u >> 16) & 1u);
  return (u16)(u >> 16);
}

// async global->LDS, 16B per lane. LDS dest must be wave-uniform base + lane*16.
__device__ __forceinline__ void gll16(const void* g, void* l){
  __builtin_amdgcn_global_load_lds((const __attribute__((address_space(1))) void*)g,
                                   (__attribute__((address_space(3))) void*)l, 16, 0, 0);
}

__global__ __launch_bounds__(256) void cvt_kernel(const float4* __restrict__ in,
                                                  ushort4* __restrict__ out, int n4){
  int i = blockIdx.x * 256 + threadIdx.x;
  if (i >= n4) return;
  float4 v = in[i];
  ushort4 o; o.x = f2bf(v.x); o.y = f2bf(v.y); o.z = f2bf(v.z); o.w = f2bf(v.w);
  out[i] = o;
}

// router: 4 tokens/block, 1 wave/token, all-register cross-lane top-k (no LDS).
__global__ __launch_bounds__(256) void router_kernel(const float* __restrict__ x,
                                                     const float* __restrict__ gate,
                                                     const float* __restrict__ ebias,
                                                     int* __restrict__ cnt,
                                                     int* __restrict__ tok,
                                                     float* __restrict__ wl){
  int wave = threadIdx.x >> 6;
  int lane = threadIdx.x & 63;
  int t = blockIdx.x * 4 + wave;
  int e = lane & 31, half = lane >> 5;
  const float4* xv = (const float4*)(x + (size_t)t * HID);
  const float4* gv = (const float4*)(gate + (size_t)e * HID);
  double d0 = 0, d1 = 0, d2 = 0, d3 = 0;
  for (int i = half * 128; i < half * 128 + 128; i++){
    float4 a = xv[i], b = gv[i];
    d0 += (double)a.x * b.x; d1 += (double)a.y * b.y;
    d2 += (double)a.z * b.z; d3 += (double)a.w * b.w;
  }
  double acc = (d0 + d1) + (d2 + d3);
  acc += __shfl_xor(acc, 32);
  double score = 1.0 / (1.0 + exp(-acc));
  double sc = score + (double)ebias[e];
  double o1  = __shfl_xor(sc, 1);
  double hi  = fmax(sc, o1), lo = fmin(sc, o1);
  double ohi = __shfl_xor(hi, 2), olo = __shfl_xor(lo, 2);
  double gs  = (hi >= ohi) ? hi + fmax(lo, ohi) : ohi + fmax(olo, hi);
  int g = e >> 2;
  int rank = 0;
#pragma unroll
  for (int j = 0; j < 8; j++){
    double gj = __shfl(gs, j * 4);
    if (gj > gs || (gj == gs && j < g)) rank++;
  }
  double cur = (rank < 4) ? sc : 0.0;
  int sel_e[TOPK]; double sel_w[TOPK]; double wsum = 0.0;
#pragma unroll
  for (int k = 0; k < TOPK; k++){
    double bv = cur; int bi = lane;
#pragma unroll
    for (int m = 32; m >= 1; m >>= 1){
      double ov = __shfl_xor(bv, m); int oi = __shfl_xor(bi, m);
      if (ov > bv || (ov == bv && oi < bi)) { bv = ov; bi = oi; }
    }
    if ((bi & 31) == e) cur = -1e300;
    double ws = __shfl(score, bi);
    sel_e[k] = bi; sel_w[k] = ws; wsum += ws;
  }
  double scale = 2.5 / (wsum + 1e-20);
#pragma unroll
  for (int k = 0; k < TOPK; k++){
    if (lane == k){
      int ee = sel_e[k];
      float wv = (float)(sel_w[k] * scale);
      int pos = atomicAdd(&cnt[ee], 1);
      tok[ee * T_TOK + pos] = (t << 3) | k;
      wl[ee * T_TOK + pos] = wv;
    }
  }
}

// build dense tile plan: plan[1+i] = (tile_base<<8)|expert for every active 128-token tile
__global__ __launch_bounds__(256) void plan_kernel(const int* __restrict__ cnt,
                                                   int* __restrict__ plan){
  int tid = threadIdx.x;
  if (tid < PLAN_MAX) plan[1 + tid] = -1;
  __syncthreads();
  if (tid == 0){
    int n = 0;
    for (int e = 0; e < NEXP; e++){
      int c = cnt[e];
      for (int tb = 0; tb < c; tb += 128) plan[1 + n++] = (tb << 8) | e;
    }
    plan[0] = n;
  }
}

// ---- m97-style core: 128x128 block tile, BK=32, 4 waves in 2x2, 4x4 MFMA acc/wave ----
__device__ __forceinline__ void gemm_core(
    const char* gA0, const char* gA1, const char* gB0, const char* gB1,
    u16* lA, u16* lB, int iters, int tid, int wrow, int wcol, int quad, int l16,
    f32x4 acc[4][4])
{
  char* dA0 = (char*)lA + tid*16;
  char* dA1 = (char*)lA + 4096 + tid*16;
  char* dB0 = (char*)lB + tid*16;
  char* dB1 = (char*)lB + 4096 + tid*16;
  for (int it = 0; it < iters; ++it){
    gll16(gA0, dA0); gll16(gA1, dA1);
    gll16(gB0, dB0); gll16(gB1, dB1);
    gA0 += 64; gA1 += 64; gB0 += 64; gB1 += 64;
    __syncthreads();
    bf16x8 af[4], bfr[4];
#pragma unroll
    for (int mt = 0; mt < 4; mt++) af[mt] = *(const bf16x8*)&lA[(wrow + mt*16 + l16)*32 + quad*8];
#pragma unroll
    for (int nt = 0; nt < 4; nt++) bfr[nt] = *(const bf16x8*)&lB[(wcol + nt*16 + l16)*32 + quad*8];
#pragma unroll
    for (int mt = 0; mt < 4; mt++)
#pragma unroll
      for (int nt = 0; nt < 4; nt++)
        acc[mt][nt] = __builtin_amdgcn_mfma_f32_16x16x32_bf16(af[mt], bfr[nt], acc[mt][nt], 0, 0, 0);
    __syncthreads();
  }
}

#define ACC_INIT f32x4 acc[4][4]; \
  _Pragma("unroll") for (int i_ = 0; i_ < 4; i_++) \
  _Pragma("unroll") for (int j_ = 0; j_ < 4; j_++) acc[i_][j_] = (f32x4){0.f,0.f,0.f,0.f};

// shared up: C[2048][2048] = bf16(relu2(X[2048][1024] . W[2048][1024]^T))
__global__ __launch_bounds__(256) void sh_up_kernel(const u16* __restrict__ A,
                                                    const u16* __restrict__ B,
                                                    u16* __restrict__ C){
  __shared__ u16 lA[128*32], lB[128*32];
  int tid = threadIdx.x;
  int bm = blockIdx.x*128, bn = blockIdx.y*128;
  int lane = tid & 63, wave = tid >> 6, quad = lane >> 4, l16 = lane & 15;
  int wrow = (wave >> 1)*64, wcol = (wave & 1)*64;
  int srow = tid >> 2, sseg = (tid & 3)*16;
  const char* gA0 = (const char*)(A + (size_t)(bm + srow)*HID) + sseg;
  const char* gA1 = (const char*)(A + (size_t)(bm + 64 + srow)*HID) + sseg;
  const char* gB0 = (const char*)(B + (size_t)(bn + srow)*HID) + sseg;
  const char* gB1 = (const char*)(B + (size_t)(bn + 64 + srow)*HID) + sseg;
  ACC_INIT;
  gemm_core(gA0, gA1, gB0, gB1, lA, lB, HID/32, tid, wrow, wcol, quad, l16, acc);
#pragma unroll
  for (int mt = 0; mt < 4; mt++)
#pragma unroll
    for (int nt = 0; nt < 4; nt++)
#pragma unroll
      for (int r = 0; r < 4; r++){
        int m = bm + wrow + mt*16 + quad*4 + r;
        int n = bn + wcol + nt*16 + l16;
        float v = acc[mt][nt][r]; v = fmaxf(v, 0.f); v *= v;
        C[(size_t)m*SI + n] = f2bf(v);
      }
}

// shared down: out[2048][1024] = H[2048][2048] . W[1024][2048]^T (fp32)
__global__ __launch_bounds__(256) void sh_down_kernel(const u16* __restrict__ A,
                                                      const u16* __restrict__ B,
                                                      float* __restrict__ C){
  __shared__ u16 lA[128*32], lB[128*32];
  int tid = threadIdx.x;
  int bm = blockIdx.x*128, bn = blockIdx.y*128;
  int lane = tid & 63, wave = tid >> 6, quad = lane >> 4, l16 = lane & 15;
  int wrow = (wave >> 1)*64, wcol = (wave & 1)*64;
  int srow = tid >> 2, sseg = (tid & 3)*16;
  const char* gA0 = (const char*)(A + (size_t)(bm + srow)*SI) + sseg;
  const char* gA1 = (const char*)(A + (size_t)(bm + 64 + srow)*SI) + sseg;
  const char* gB0 = (const char*)(B + (size_t)(bn + srow)*SI) + sseg;
  const char* gB1 = (const char*)(B + (size_t)(bn + 64 + srow)*SI) + sseg;
  ACC_INIT;
  gemm_core(gA0, gA1, gB0, gB1, lA, lB, SI/32, tid, wrow, wcol, quad, l16, acc);
#pragma unroll
  for (int mt = 0; mt < 4; mt++)
#pragma unroll
    for (int nt = 0; nt < 4; nt++)
#pragma unroll
      for (int r = 0; r < 4; r++){
        int m = bm + wrow + mt*16 + quad*4 + r;
        int n = bn + wcol + nt*16 + l16;
        C[(size_t)m*HID + n] = acc[mt][nt][r];
      }
}

// expert up: hws[t*6+k][512] = bf16(relu2(x_t . up_e^T) * w)
__global__ __launch_bounds__(256) void expert_up_kernel(const u16* __restrict__ xb,
                                                        const u16* __restrict__ upb,
                                                        const int* __restrict__ cnt,
                                                        const int* __restrict__ tok,
                                                        const float* __restrict__ wl,
                                                        const int* __restrict__ plan,
                                                        u16* __restrict__ hws){
  int pv = plan[1 + blockIdx.x];
  if (pv < 0) return;
  int e = pv & 255;
  int tb = pv >> 8;
  int c = cnt[e];
  int bn = blockIdx.y * 128;
  const int* tl = tok + e * T_TOK;
  const float* wle = wl + e * T_TOK;
  __shared__ u16 lA[128*32], lB[128*32];
  int tid = threadIdx.x;
  int lane = tid & 63, wave = tid >> 6, quad = lane >> 4, l16 = lane & 15;
  int wrow = (wave >> 1)*64, wcol = (wave & 1)*64;
  int srow = tid >> 2, sseg = (tid & 3)*16;
  int s0 = tb + srow;      if (s0 > c-1) s0 = c-1;
  int s1 = tb + 64 + srow; if (s1 > c-1) s1 = c-1;
  int t0 = tl[s0] >> 3, t1 = tl[s1] >> 3;
  const char* gA0 = (const char*)(xb + (size_t)t0*HID) + sseg;
  const char* gA1 = (const char*)(xb + (size_t)t1*HID) + sseg;
  const u16* Bb = upb + (size_t)e * IM * HID;
  const char* gB0 = (const char*)(Bb + (size_t)(bn + srow)*HID) + sseg;
  const char* gB1 = (const char*)(Bb + (size_t)(bn + 64 + srow)*HID) + sseg;
  ACC_INIT;
  gemm_core(gA0, gA1, gB0, gB1, lA, lB, HID/32, tid, wrow, wcol, quad, l16, acc);
#pragma unroll
  for (int mt = 0; mt < 4; mt++)
#pragma unroll
    for (int r = 0; r < 4; r++){
      int s = tb + wrow + mt*16 + quad*4 + r;
      if (s < c){
        int code = tl[s];
        float w = wle[s];
        size_t hb = ((size_t)(code >> 3) * TOPK + (code & 7)) * IM;
#pragma unroll
        for (int nt = 0; nt < 4; nt++){
          float v = acc[mt][nt][r]; v = fmaxf(v, 0.f); v = v * v * w;
          hws[hb + bn + wcol + nt*16 + l16] = f2bf(v);
        }
      }
    }
}

// expert down: dws[t*6+k][1024] = h_slot . down_e^T (fp32, no atomics)
__global__ __launch_bounds__(256) void expert_down_kernel(const u16* __restrict__ hws,
                                                          const u16* __restrict__ dnb,
                                                          const int* __restrict__ cnt,
                                                          const int* __restrict__ tok,
                                                          const int* __restrict__ plan,
                                                          float* __restrict__ dws){
  int pv = plan[1 + blockIdx.x];
  if (pv < 0) return;
  int e = pv & 255;
  int tb = pv >> 8;
  int c = cnt[e];
  int bn = blockIdx.y * 128;
  const int* tl = tok + e * T_TOK;
  __shared__ u16 lA[128*32], lB[128*32];
  int tid = threadIdx.x;
  int lane = tid & 63, wave = tid >> 6, quad = lane >> 4, l16 = lane & 15;
  int wrow = (wave >> 1)*64, wcol = (wave & 1)*64;
  int srow = tid >> 2, sseg = (tid & 3)*16;
  int s0 = tb + srow;      if (s0 > c-1) s0 = c-1;
  int s1 = tb + 64 + srow; if (s1 > c-1) s1 = c-1;
  int c0 = tl[s0], c1 = tl[s1];
  const char* gA0 = (const char*)(hws + ((size_t)(c0 >> 3)*TOPK + (c0 & 7))*IM) + sseg;
  const char* gA1 = (const char*)(hws + ((size_t)(c1 >> 3)*TOPK + (c1 & 7))*IM) + sseg;
  const u16* Bb = dnb + (size_t)e * HID * IM;
  const char* gB0 = (const char*)(Bb + (size_t)(bn + srow)*IM) + sseg;
  const char* gB1 = (const char*)(Bb + (size_t)(bn + 64 + srow)*IM) + sseg;
  ACC_INIT;
  gemm_core(gA0, gA1, gB0, gB1, lA, lB, IM/32, tid, wrow, wcol, quad, l16, acc);
#pragma unroll
  for (int mt = 0; mt < 4; mt++)
#pragma unroll
    for (int r = 0; r < 4; r++){
      int s = tb + wrow + mt*16 + quad*4 + r;
      if (s < c){
        int code = tl[s];
        size_t db = ((size_t)(code >> 3) * TOPK + (code & 7)) * HID;
#pragma unroll
        for (int nt = 0; nt < 4; nt++)
          dws[db + bn + wcol + nt*16 + l16] = acc[mt][nt][r];
      }
    }
}

// out[t][h] += sum_k dws[t*6+k][h]
__global__ __launch_bounds__(256) void reduce_kernel(const float4* __restrict__ dws,
                                                     float4* __restrict__ out){
  int i = blockIdx.x * 256 + threadIdx.x;
  int t = i >> 8;
  int col = i & 255;
  const float4* p = dws + (size_t)t * TOPK * 256 + col;
  float4 s = out[i];
#pragma unroll
  for (int k = 0; k < TOPK; k++){
    float4 v = p[(size_t)k * 256];
    s.x += v.x; s.y += v.y; s.z += v.z; s.w += v.w;
  }
  out[i] = s;
}

extern "C" void kernel_launch(void* const* d_in, const int* in_sizes, int n_in,
                              void* d_out, int out_size, void* d_ws, size_t ws_size,
                              hipStream_t stream) {
  const float* x    = (const float*)d_in[0];
  const float* gate = (const float*)d_in[1];
  const float* eb   = (const float*)d_in[2];
  const float* upw  = (const float*)d_in[3];
  const float* dnw  = (const float*)d_in[4];
  const float* supw = (const float*)d_in[5];
  const float* sdnw = (const float*)d_in[6];
  float* out = (float*)d_out;

  char* w = (char*)d_ws;
  size_t o = 0;
  int*   cnt  = (int*)(w + o);   o += 1024;
  int*   plan = (int*)(w + o);   o += 1024;
  int*   tok  = (int*)(w + o);   o += (size_t)NEXP * T_TOK * 4;
  float* wl   = (float*)(w + o); o += (size_t)NEXP * T_TOK * 4;
  u16*   xb   = (u16*)(w + o);   o += (size_t)T_TOK * HID * 2;
  u16*   dnb  = (u16*)(w + o);   o += (size_t)NEXP * HID * IM * 2;
  u16*   hws  = (u16*)(w + o);   o += (size_t)T_TOK * TOPK * IM * 2;
  // region reused: [upb | supb | sdnb | shh] all dead once expert_down runs -> dws aliases it
  size_t region = o;
  u16*   upb  = (u16*)(w + o);   o += (size_t)NEXP * IM * HID * 2;   // 32MB
  u16*   supb = (u16*)(w + o);   o += (size_t)SI * HID * 2;          // 8MB
  u16*   sdnb = (u16*)(w + o);   o += (size_t)HID * SI * 2;          // 8MB
  u16*   shh  = (u16*)(w + o);   o += (size_t)T_TOK * SI * 2;        // 8MB
  float* dws  = (float*)(w + region);  // 48MB <= 56MB region

  hipMemsetAsync(cnt, 0, 1024, stream);

  auto cv = [&](const float* src, u16* dst, int n){
    int n4 = n / 4;
    cvt_kernel<<<(n4 + 255) / 256, 256, 0, stream>>>((const float4*)src, (ushort4*)dst, n4);
  };
  cv(x,    xb,   T_TOK * HID);
  cv(upw,  upb,  NEXP * IM * HID);
  cv(dnw,  dnb,  NEXP * HID * IM);
  cv(supw, supb, SI * HID);
  cv(sdnw, sdnb, HID * SI);

  router_kernel<<<T_TOK/4, 256, 0, stream>>>(x, gate, eb, cnt, tok, wl);
  plan_kernel<<<1, 256, 0, stream>>>(cnt, plan);

  sh_up_kernel<<<dim3(T_TOK/128, SI/128), 256, 0, stream>>>(xb, supb, shh);
  sh_down_kernel<<<dim3(T_TOK/128, HID/128), 256, 0, stream>>>(shh, sdnb, out);

  expert_up_kernel<<<dim3(PLAN_MAX, IM/128), 256, 0, stream>>>(xb, upb, cnt, tok, wl, plan, hws);
  expert_down_kernel<<<dim3(PLAN_MAX, HID/128), 256, 0, stream>>>(hws, dnb, cnt, tok, plan, dws);

  reduce_kernel<<<(T_TOK * HID / 4) / 256, 256, 0, stream>>>((const float4*)dws, (float4*)out);
}

// Round 5
// 391.582 us; speedup vs baseline: 1.7964x; 1.1376x over previous
//
#include <hip/hip_runtime.h>

typedef unsigned short u16;
typedef __bf16 bf16x8 __attribute__((ext_vector_type(8)));
typedef float f32x4 __attribute__((ext_vector_type(4)));

#define T_TOK 2048
#define HID   1024
#define NEXP  32
#define IM    512
#define SI    2048
#define TOPK  6
#define PLAN_MAX 160

// exact RNE float->bf16
__device__ __forceinline__ u16 f2bf(float f){
  unsigned u = __float_as_uint(f);
  u += 0x7FFFu + ((u >> 16) & 1u);
  return (u16)(u >> 16);
}

// async global->LDS, 16B per lane. LDS dest must be wave-uniform base + lane*16.
__device__ __forceinline__ void gll16(const void* g, void* l){
  __builtin_amdgcn_global_load_lds((const __attribute__((address_space(1))) void*)g,
                                   (__attribute__((address_space(3))) void*)l, 16, 0, 0);
}

// one fused conversion kernel over 5 concatenated fp32 regions (each region a
// multiple of 256 float4 -> every block maps to exactly one region)
__global__ __launch_bounds__(256) void cvt_all_kernel(const float4* __restrict__ s0, // x      524288
                                                      const float4* __restrict__ s1, // upw   4194304
                                                      const float4* __restrict__ s2, // dnw   4194304
                                                      const float4* __restrict__ s3, // supw   524288
                                                      const float4* __restrict__ s4, // sdnw   524288
                                                      ushort4* __restrict__ d0,
                                                      ushort4* __restrict__ d1,
                                                      ushort4* __restrict__ d2,
                                                      ushort4* __restrict__ d3,
                                                      ushort4* __restrict__ d4){
  long i = (long)blockIdx.x * 256 + threadIdx.x;
  const float4* s; ushort4* d;
  if      (i <  524288L)                 { s = s0;            d = d0;            }
  else if (i <  524288L + 4194304L)      { s = s1 - 524288L;  d = d1 - 524288L;  }
  else if (i <  524288L + 8388608L)      { s = s2 - 4718592L; d = d2 - 4718592L; }
  else if (i <  524288L + 8912896L)      { s = s3 - 8912896L; d = d3 - 8912896L; }
  else                                   { s = s4 - 9437184L; d = d4 - 9437184L; }
  float4 v = s[i];
  ushort4 o; o.x = f2bf(v.x); o.y = f2bf(v.y); o.z = f2bf(v.z); o.w = f2bf(v.w);
  d[i] = o;
}

// router: 4 tokens/block, 1 wave/token, all-register cross-lane top-k, NO atomics.
// writes dense per-token choices ce[t*6+k] (expert id), cw[t*6+k] (weight).
__global__ __launch_bounds__(256) void router_kernel(const float* __restrict__ x,
                                                     const float* __restrict__ gate,
                                                     const float* __restrict__ ebias,
                                                     int* __restrict__ ce,
                                                     float* __restrict__ cw){
  int wave = threadIdx.x >> 6;
  int lane = threadIdx.x & 63;
  int t = blockIdx.x * 4 + wave;
  int e = lane & 31, half = lane >> 5;
  const float4* xv = (const float4*)(x + (size_t)t * HID);
  const float4* gv = (const float4*)(gate + (size_t)e * HID);
  double d0 = 0, d1 = 0, d2 = 0, d3 = 0;
  for (int i = half * 128; i < half * 128 + 128; i++){
    float4 a = xv[i], b = gv[i];
    d0 += (double)a.x * b.x; d1 += (double)a.y * b.y;
    d2 += (double)a.z * b.z; d3 += (double)a.w * b.w;
  }
  double acc = (d0 + d1) + (d2 + d3);
  acc += __shfl_xor(acc, 32);
  double score = 1.0 / (1.0 + exp(-acc));
  double sc = score + (double)ebias[e];
  double o1  = __shfl_xor(sc, 1);
  double hi  = fmax(sc, o1), lo = fmin(sc, o1);
  double ohi = __shfl_xor(hi, 2), olo = __shfl_xor(lo, 2);
  double gs  = (hi >= ohi) ? hi + fmax(lo, ohi) : ohi + fmax(olo, hi);
  int g = e >> 2;
  int rank = 0;
#pragma unroll
  for (int j = 0; j < 8; j++){
    double gj = __shfl(gs, j * 4);
    if (gj > gs || (gj == gs && j < g)) rank++;
  }
  double cur = (rank < 4) ? sc : 0.0;
  int sel_e[TOPK]; double sel_w[TOPK]; double wsum = 0.0;
#pragma unroll
  for (int k = 0; k < TOPK; k++){
    double bv = cur; int bi = lane;
#pragma unroll
    for (int m = 32; m >= 1; m >>= 1){
      double ov = __shfl_xor(bv, m); int oi = __shfl_xor(bi, m);
      if (ov > bv || (ov == bv && oi < bi)) { bv = ov; bi = oi; }
    }
    if ((bi & 31) == e) cur = -1e300;
    double ws = __shfl(score, bi);
    sel_e[k] = bi; sel_w[k] = ws; wsum += ws;
  }
  double scale = 2.5 / (wsum + 1e-20);
#pragma unroll
  for (int k = 0; k < TOPK; k++){
    if (lane == k){                       // compile-time idx -> no scratch spill
      ce[t * TOPK + k] = sel_e[k] & 31;
      cw[t * TOPK + k] = (float)(sel_w[k] * scale);
    }
  }
}

// 32 blocks (one per expert): ordered compaction of the 12288 choices into
// per-expert token lists via ballot prefix scan. Deterministic, token-sorted.
__global__ __launch_bounds__(256) void build_kernel(const int* __restrict__ ce,
                                                    const float* __restrict__ cw,
                                                    int* __restrict__ cnt,
                                                    int* __restrict__ tok,
                                                    float* __restrict__ wl){
  int e = blockIdx.x;
  int tid = threadIdx.x, lane = tid & 63, wave = tid >> 6;
  __shared__ int wsum[4];
  int running = 0;
  for (int base = 0; base < T_TOK * TOPK; base += 256){
    int i = base + tid;                       // 12288 = 48*256, no bounds check
    bool m = (ce[i] == e);
    unsigned long long bal = __ballot(m);
    int woff = __popcll(bal & ((1ull << lane) - 1ull));
    if (lane == 0) wsum[wave] = __popcll(bal);
    __syncthreads();
    int wbase = 0;
#pragma unroll
    for (int wv = 0; wv < 4; wv++) if (wv < wave) wbase += wsum[wv];
    int btot = wsum[0] + wsum[1] + wsum[2] + wsum[3];
    if (m){
      int t = i / TOPK, k = i - t * TOPK;
      int pos = running + wbase + woff;
      tok[e * T_TOK + pos] = (t << 3) | k;
      wl[e * T_TOK + pos] = cw[i];
    }
    running += btot;
    __syncthreads();                          // wsum WAR hazard for next iter
  }
  if (tid == 0) cnt[e] = running;
}

// build dense tile plan: plan[1+i] = (tile_base<<8)|expert for every active 128-token tile
__global__ __launch_bounds__(256) void plan_kernel(const int* __restrict__ cnt,
                                                   int* __restrict__ plan){
  int tid = threadIdx.x;
  if (tid < PLAN_MAX) plan[1 + tid] = -1;
  __syncthreads();
  if (tid == 0){
    int n = 0;
    for (int e = 0; e < NEXP; e++){
      int c = cnt[e];
      for (int tb = 0; tb < c; tb += 128) plan[1 + n++] = (tb << 8) | e;
    }
    plan[0] = n;
  }
}

// ---- m97-style core: 128x128 block tile, BK=32, 4 waves in 2x2, 4x4 MFMA acc/wave ----
__device__ __forceinline__ void gemm_core(
    const char* gA0, const char* gA1, const char* gB0, const char* gB1,
    u16* lA, u16* lB, int iters, int tid, int wrow, int wcol, int quad, int l16,
    f32x4 acc[4][4])
{
  char* dA0 = (char*)lA + tid*16;
  char* dA1 = (char*)lA + 4096 + tid*16;
  char* dB0 = (char*)lB + tid*16;
  char* dB1 = (char*)lB + 4096 + tid*16;
  for (int it = 0; it < iters; ++it){
    gll16(gA0, dA0); gll16(gA1, dA1);
    gll16(gB0, dB0); gll16(gB1, dB1);
    gA0 += 64; gA1 += 64; gB0 += 64; gB1 += 64;
    __syncthreads();
    bf16x8 af[4], bfr[4];
#pragma unroll
    for (int mt = 0; mt < 4; mt++) af[mt] = *(const bf16x8*)&lA[(wrow + mt*16 + l16)*32 + quad*8];
#pragma unroll
    for (int nt = 0; nt < 4; nt++) bfr[nt] = *(const bf16x8*)&lB[(wcol + nt*16 + l16)*32 + quad*8];
#pragma unroll
    for (int mt = 0; mt < 4; mt++)
#pragma unroll
      for (int nt = 0; nt < 4; nt++)
        acc[mt][nt] = __builtin_amdgcn_mfma_f32_16x16x32_bf16(af[mt], bfr[nt], acc[mt][nt], 0, 0, 0);
    __syncthreads();
  }
}

#define ACC_INIT f32x4 acc[4][4]; \
  _Pragma("unroll") for (int i_ = 0; i_ < 4; i_++) \
  _Pragma("unroll") for (int j_ = 0; j_ < 4; j_++) acc[i_][j_] = (f32x4){0.f,0.f,0.f,0.f};

// shared up: C[2048][2048] = bf16(relu2(X[2048][1024] . W[2048][1024]^T))
__global__ __launch_bounds__(256) void sh_up_kernel(const u16* __restrict__ A,
                                                    const u16* __restrict__ B,
                                                    u16* __restrict__ C){
  __shared__ u16 lA[128*32], lB[128*32];
  int tid = threadIdx.x;
  int bm = blockIdx.x*128, bn = blockIdx.y*128;
  int lane = tid & 63, wave = tid >> 6, quad = lane >> 4, l16 = lane & 15;
  int wrow = (wave >> 1)*64, wcol = (wave & 1)*64;
  int srow = tid >> 2, sseg = (tid & 3)*16;
  const char* gA0 = (const char*)(A + (size_t)(bm + srow)*HID) + sseg;
  const char* gA1 = (const char*)(A + (size_t)(bm + 64 + srow)*HID) + sseg;
  const char* gB0 = (const char*)(B + (size_t)(bn + srow)*HID) + sseg;
  const char* gB1 = (const char*)(B + (size_t)(bn + 64 + srow)*HID) + sseg;
  ACC_INIT;
  gemm_core(gA0, gA1, gB0, gB1, lA, lB, HID/32, tid, wrow, wcol, quad, l16, acc);
#pragma unroll
  for (int mt = 0; mt < 4; mt++)
#pragma unroll
    for (int nt = 0; nt < 4; nt++)
#pragma unroll
      for (int r = 0; r < 4; r++){
        int m = bm + wrow + mt*16 + quad*4 + r;
        int n = bn + wcol + nt*16 + l16;
        float v = acc[mt][nt][r]; v = fmaxf(v, 0.f); v *= v;
        C[(size_t)m*SI + n] = f2bf(v);
      }
}

// shared down: out[2048][1024] = H[2048][2048] . W[1024][2048]^T (fp32)
__global__ __launch_bounds__(256) void sh_down_kernel(const u16* __restrict__ A,
                                                      const u16* __restrict__ B,
                                                      float* __restrict__ C){
  __shared__ u16 lA[128*32], lB[128*32];
  int tid = threadIdx.x;
  int bm = blockIdx.x*128, bn = blockIdx.y*128;
  int lane = tid & 63, wave = tid >> 6, quad = lane >> 4, l16 = lane & 15;
  int wrow = (wave >> 1)*64, wcol = (wave & 1)*64;
  int srow = tid >> 2, sseg = (tid & 3)*16;
  const char* gA0 = (const char*)(A + (size_t)(bm + srow)*SI) + sseg;
  const char* gA1 = (const char*)(A + (size_t)(bm + 64 + srow)*SI) + sseg;
  const char* gB0 = (const char*)(B + (size_t)(bn + srow)*SI) + sseg;
  const char* gB1 = (const char*)(B + (size_t)(bn + 64 + srow)*SI) + sseg;
  ACC_INIT;
  gemm_core(gA0, gA1, gB0, gB1, lA, lB, SI/32, tid, wrow, wcol, quad, l16, acc);
#pragma unroll
  for (int mt = 0; mt < 4; mt++)
#pragma unroll
    for (int nt = 0; nt < 4; nt++)
#pragma unroll
      for (int r = 0; r < 4; r++){
        int m = bm + wrow + mt*16 + quad*4 + r;
        int n = bn + wcol + nt*16 + l16;
        C[(size_t)m*HID + n] = acc[mt][nt][r];
      }
}

// expert up: hws[t*6+k][512] = bf16(relu2(x_t . up_e^T) * w)
__global__ __launch_bounds__(256) void expert_up_kernel(const u16* __restrict__ xb,
                                                        const u16* __restrict__ upb,
                                                        const int* __restrict__ cnt,
                                                        const int* __restrict__ tok,
                                                        const float* __restrict__ wl,
                                                        const int* __restrict__ plan,
                                                        u16* __restrict__ hws){
  int pv = plan[1 + blockIdx.x];
  if (pv < 0) return;
  int e = pv & 255;
  int tb = pv >> 8;
  int c = cnt[e];
  int bn = blockIdx.y * 128;
  const int* tl = tok + e * T_TOK;
  const float* wle = wl + e * T_TOK;
  __shared__ u16 lA[128*32], lB[128*32];
  int tid = threadIdx.x;
  int lane = tid & 63, wave = tid >> 6, quad = lane >> 4, l16 = lane & 15;
  int wrow = (wave >> 1)*64, wcol = (wave & 1)*64;
  int srow = tid >> 2, sseg = (tid & 3)*16;
  int s0 = tb + srow;      if (s0 > c-1) s0 = c-1;
  int s1 = tb + 64 + srow; if (s1 > c-1) s1 = c-1;
  int t0 = tl[s0] >> 3, t1 = tl[s1] >> 3;
  const char* gA0 = (const char*)(xb + (size_t)t0*HID) + sseg;
  const char* gA1 = (const char*)(xb + (size_t)t1*HID) + sseg;
  const u16* Bb = upb + (size_t)e * IM * HID;
  const char* gB0 = (const char*)(Bb + (size_t)(bn + srow)*HID) + sseg;
  const char* gB1 = (const char*)(Bb + (size_t)(bn + 64 + srow)*HID) + sseg;
  ACC_INIT;
  gemm_core(gA0, gA1, gB0, gB1, lA, lB, HID/32, tid, wrow, wcol, quad, l16, acc);
#pragma unroll
  for (int mt = 0; mt < 4; mt++)
#pragma unroll
    for (int r = 0; r < 4; r++){
      int s = tb + wrow + mt*16 + quad*4 + r;
      if (s < c){
        int code = tl[s];
        float w = wle[s];
        size_t hb = ((size_t)(code >> 3) * TOPK + (code & 7)) * IM;
#pragma unroll
        for (int nt = 0; nt < 4; nt++){
          float v = acc[mt][nt][r]; v = fmaxf(v, 0.f); v = v * v * w;
          hws[hb + bn + wcol + nt*16 + l16] = f2bf(v);
        }
      }
    }
}

// expert down: dws[t*6+k][1024] = h_slot . down_e^T (fp32, no atomics)
__global__ __launch_bounds__(256) void expert_down_kernel(const u16* __restrict__ hws,
                                                          const u16* __restrict__ dnb,
                                                          const int* __restrict__ cnt,
                                                          const int* __restrict__ tok,
                                                          const int* __restrict__ plan,
                                                          float* __restrict__ dws){
  int pv = plan[1 + blockIdx.x];
  if (pv < 0) return;
  int e = pv & 255;
  int tb = pv >> 8;
  int c = cnt[e];
  int bn = blockIdx.y * 128;
  const int* tl = tok + e * T_TOK;
  __shared__ u16 lA[128*32], lB[128*32];
  int tid = threadIdx.x;
  int lane = tid & 63, wave = tid >> 6, quad = lane >> 4, l16 = lane & 15;
  int wrow = (wave >> 1)*64, wcol = (wave & 1)*64;
  int srow = tid >> 2, sseg = (tid & 3)*16;
  int s0 = tb + srow;      if (s0 > c-1) s0 = c-1;
  int s1 = tb + 64 + srow; if (s1 > c-1) s1 = c-1;
  int c0 = tl[s0], c1 = tl[s1];
  const char* gA0 = (const char*)(hws + ((size_t)(c0 >> 3)*TOPK + (c0 & 7))*IM) + sseg;
  const char* gA1 = (const char*)(hws + ((size_t)(c1 >> 3)*TOPK + (c1 & 7))*IM) + sseg;
  const u16* Bb = dnb + (size_t)e * HID * IM;
  const char* gB0 = (const char*)(Bb + (size_t)(bn + srow)*IM) + sseg;
  const char* gB1 = (const char*)(Bb + (size_t)(bn + 64 + srow)*IM) + sseg;
  ACC_INIT;
  gemm_core(gA0, gA1, gB0, gB1, lA, lB, IM/32, tid, wrow, wcol, quad, l16, acc);
#pragma unroll
  for (int mt = 0; mt < 4; mt++)
#pragma unroll
    for (int r = 0; r < 4; r++){
      int s = tb + wrow + mt*16 + quad*4 + r;
      if (s < c){
        int code = tl[s];
        size_t db = ((size_t)(code >> 3) * TOPK + (code & 7)) * HID;
#pragma unroll
        for (int nt = 0; nt < 4; nt++)
          dws[db + bn + wcol + nt*16 + l16] = acc[mt][nt][r];
      }
    }
}

// out[t][h] += sum_k dws[t*6+k][h]
__global__ __launch_bounds__(256) void reduce_kernel(const float4* __restrict__ dws,
                                                     float4* __restrict__ out){
  int i = blockIdx.x * 256 + threadIdx.x;
  int t = i >> 8;
  int col = i & 255;
  const float4* p = dws + (size_t)t * TOPK * 256 + col;
  float4 s = out[i];
#pragma unroll
  for (int k = 0; k < TOPK; k++){
    float4 v = p[(size_t)k * 256];
    s.x += v.x; s.y += v.y; s.z += v.z; s.w += v.w;
  }
  out[i] = s;
}

extern "C" void kernel_launch(void* const* d_in, const int* in_sizes, int n_in,
                              void* d_out, int out_size, void* d_ws, size_t ws_size,
                              hipStream_t stream) {
  const float* x    = (const float*)d_in[0];
  const float* gate = (const float*)d_in[1];
  const float* eb   = (const float*)d_in[2];
  const float* upw  = (const float*)d_in[3];
  const float* dnw  = (const float*)d_in[4];
  const float* supw = (const float*)d_in[5];
  const float* sdnw = (const float*)d_in[6];
  float* out = (float*)d_out;

  char* w = (char*)d_ws;
  size_t o = 0;
  int*   cnt  = (int*)(w + o);   o += 1024;
  int*   plan = (int*)(w + o);   o += 1024;
  int*   ce   = (int*)(w + o);   o += (size_t)T_TOK * TOPK * 4;
  float* cw   = (float*)(w + o); o += (size_t)T_TOK * TOPK * 4;
  int*   tok  = (int*)(w + o);   o += (size_t)NEXP * T_TOK * 4;
  float* wl   = (float*)(w + o); o += (size_t)NEXP * T_TOK * 4;
  u16*   xb   = (u16*)(w + o);   o += (size_t)T_TOK * HID * 2;
  u16*   dnb  = (u16*)(w + o);   o += (size_t)NEXP * HID * IM * 2;
  u16*   hws  = (u16*)(w + o);   o += (size_t)T_TOK * TOPK * IM * 2;
  // region reused: [upb | supb | sdnb | shh] all dead once expert_down runs -> dws aliases it
  size_t region = o;
  u16*   upb  = (u16*)(w + o);   o += (size_t)NEXP * IM * HID * 2;   // 32MB
  u16*   supb = (u16*)(w + o);   o += (size_t)SI * HID * 2;          // 8MB
  u16*   sdnb = (u16*)(w + o);   o += (size_t)HID * SI * 2;          // 8MB
  u16*   shh  = (u16*)(w + o);   o += (size_t)T_TOK * SI * 2;        // 8MB
  float* dws  = (float*)(w + region);  // 48MB <= 56MB region

  // fused conversion: x | upw | dnw | supw | sdnw  (9,961,472 float4 total)
  cvt_all_kernel<<<9961472 / 256, 256, 0, stream>>>(
      (const float4*)x, (const float4*)upw, (const float4*)dnw,
      (const float4*)supw, (const float4*)sdnw,
      (ushort4*)xb, (ushort4*)upb, (ushort4*)dnb, (ushort4*)supb, (ushort4*)sdnb);

  router_kernel<<<T_TOK/4, 256, 0, stream>>>(x, gate, eb, ce, cw);
  build_kernel<<<NEXP, 256, 0, stream>>>(ce, cw, cnt, tok, wl);
  plan_kernel<<<1, 256, 0, stream>>>(cnt, plan);

  sh_up_kernel<<<dim3(T_TOK/128, SI/128), 256, 0, stream>>>(xb, supb, shh);
  sh_down_kernel<<<dim3(T_TOK/128, HID/128), 256, 0, stream>>>(shh, sdnb, out);

  expert_up_kernel<<<dim3(PLAN_MAX, IM/128), 256, 0, stream>>>(xb, upb, cnt, tok, wl, plan, hws);
  expert_down_kernel<<<dim3(PLAN_MAX, HID/128), 256, 0, stream>>>(hws, dnb, cnt, tok, plan, dws);

  reduce_kernel<<<(T_TOK * HID / 4) / 256, 256, 0, stream>>>((const float4*)dws, (float4*)out);
}